// Round 1
// baseline (163.764 us; speedup 1.0000x reference)
//
#include <hip/hip_runtime.h>

// Problem constants
#define NBATCH 8
#define NLQ    256
#define NLK    1024
#define NDQ    512
#define NDV    512
#define NH     128
#define NEGV   -1000000.0f
#define TANH_SCALE 2.8853900817779268f   // 2*log2(e)
#define LOG2E      1.4426950408889634f

__device__ __forceinline__ float fast_exp2(float x) {
#if __has_builtin(__builtin_amdgcn_exp2f)
  return __builtin_amdgcn_exp2f(x);
#else
  return exp2f(x);
#endif
}
__device__ __forceinline__ float fast_rcp(float x) {
#if __has_builtin(__builtin_amdgcn_rcpf)
  return __builtin_amdgcn_rcpf(x);
#else
  return 1.0f / x;
#endif
}

// ---------------------------------------------------------------------------
// Generic 64x64 fp32 tile GEMM: C[m0:m0+64, n0:n0+64] = A(MxK) @ B(KxN)
// 256 threads, 4x4 per thread, KT=32, A staged transposed. K%32==0 assumed.
// ---------------------------------------------------------------------------
__device__ __forceinline__ void gemm_tile64(const float* __restrict__ A,
                                            const float* __restrict__ Bm,
                                            float* __restrict__ C,
                                            int N, int K, int m0, int n0) {
  __shared__ float As[32][68];  // As[kk][m], padded
  __shared__ float Bs[32][68];  // Bs[kk][n], padded
  const int tid = threadIdx.x;
  const int tx = tid & 15, ty = tid >> 4;
  const int ar = tid >> 2;          // 0..63 : row within A tile
  const int ac = (tid & 3) * 8;     // kk offset for A stage
  const int brk = tid >> 3;         // 0..31 : kk row for B stage
  const int bnc = (tid & 7) * 8;    // col offset for B stage

  float acc[4][4] = {};

  for (int k0 = 0; k0 < K; k0 += 32) {
    const float4 a0 = *(const float4*)&A[(m0 + ar) * K + k0 + ac];
    const float4 a1 = *(const float4*)&A[(m0 + ar) * K + k0 + ac + 4];
    const float4 b0 = *(const float4*)&Bm[(k0 + brk) * N + n0 + bnc];
    const float4 b1 = *(const float4*)&Bm[(k0 + brk) * N + n0 + bnc + 4];
    __syncthreads();  // protect previous iteration's LDS reads
    As[ac + 0][ar] = a0.x; As[ac + 1][ar] = a0.y;
    As[ac + 2][ar] = a0.z; As[ac + 3][ar] = a0.w;
    As[ac + 4][ar] = a1.x; As[ac + 5][ar] = a1.y;
    As[ac + 6][ar] = a1.z; As[ac + 7][ar] = a1.w;
    *(float4*)&Bs[brk][bnc]     = b0;
    *(float4*)&Bs[brk][bnc + 4] = b1;
    __syncthreads();
#pragma unroll
    for (int kk = 0; kk < 32; ++kk) {
      const float4 a4 = *(const float4*)&As[kk][ty * 4];
      const float4 b4 = *(const float4*)&Bs[kk][tx * 4];
      acc[0][0] = fmaf(a4.x, b4.x, acc[0][0]);
      acc[0][1] = fmaf(a4.x, b4.y, acc[0][1]);
      acc[0][2] = fmaf(a4.x, b4.z, acc[0][2]);
      acc[0][3] = fmaf(a4.x, b4.w, acc[0][3]);
      acc[1][0] = fmaf(a4.y, b4.x, acc[1][0]);
      acc[1][1] = fmaf(a4.y, b4.y, acc[1][1]);
      acc[1][2] = fmaf(a4.y, b4.z, acc[1][2]);
      acc[1][3] = fmaf(a4.y, b4.w, acc[1][3]);
      acc[2][0] = fmaf(a4.z, b4.x, acc[2][0]);
      acc[2][1] = fmaf(a4.z, b4.y, acc[2][1]);
      acc[2][2] = fmaf(a4.z, b4.z, acc[2][2]);
      acc[2][3] = fmaf(a4.z, b4.w, acc[2][3]);
      acc[3][0] = fmaf(a4.w, b4.x, acc[3][0]);
      acc[3][1] = fmaf(a4.w, b4.y, acc[3][1]);
      acc[3][2] = fmaf(a4.w, b4.z, acc[3][2]);
      acc[3][3] = fmaf(a4.w, b4.w, acc[3][3]);
    }
  }
#pragma unroll
  for (int i = 0; i < 4; ++i) {
    float4 v = make_float4(acc[i][0], acc[i][1], acc[i][2], acc[i][3]);
    *(float4*)&C[(m0 + ty * 4 + i) * N + n0 + tx * 4] = v;
  }
}

// Fused projections: blocks [0,32) -> q = Q@Wq (M=2048), [32,160) -> k = K@Wk (M=8192)
__global__ __launch_bounds__(256)
void proj_kernel(const float* __restrict__ Q, const float* __restrict__ Kin,
                 const float* __restrict__ Wq, const float* __restrict__ Wk,
                 float* __restrict__ qp, float* __restrict__ kp) {
  int bx = blockIdx.x;
  const bool isQ = (bx < 32);
  const float* A = isQ ? Q : Kin;
  const float* W = isQ ? Wq : Wk;
  float* C = isQ ? qp : kp;
  if (!isQ) bx -= 32;
  gemm_tile64(A, W, C, NH, NDQ, bx * 64, blockIdx.y * 64);
}

// PV: out[b] = attn[b] (256x1024) @ V[b] (1024x512)
__global__ __launch_bounds__(256)
void pv_kernel(const float* __restrict__ attn, const float* __restrict__ V,
               float* __restrict__ out) {
  const int b = blockIdx.z;
  gemm_tile64(attn + b * (NLQ * NLK), V + b * (NLK * NDV), out + b * (NLQ * NDV),
              NDV, NLK, blockIdx.x * 64, blockIdx.y * 64);
}

// ---------------------------------------------------------------------------
// Scores + masked softmax. Block = 512 threads = 8 waves; wave w owns q-row
// q0+w. Per key-tile of 64, lane l computes score(q0+w, key0+l) by reducing
// over H=128: tanh(q+k)*w_v = Wsum + sum((-2w)*rcp(1+2^((q+k)*2log2e))).
// ---------------------------------------------------------------------------
__global__ __launch_bounds__(512)
void scores_softmax_kernel(const float* __restrict__ qp, const float* __restrict__ kp,
                           const float* __restrict__ wv, const int* __restrict__ vlen,
                           float* __restrict__ attn) {
  const int b = blockIdx.y;
  const int q0 = blockIdx.x * 8;
  const int tid = threadIdx.x;
  const int wq = tid >> 6;    // wave index -> q row
  const int lane = tid & 63;

  __shared__ float qs[8][128];
  __shared__ float ks[64][129];   // +1 pad: per-key reads conflict-free
  __shared__ float wls[128];

  // stage q rows (pre-scaled by 2*log2e)
  {
    const int e = tid * 2;
    const int r = e >> 7, c = e & 127;
    const float2 v = *(const float2*)&qp[(b * NLQ + q0 + r) * NH + c];
    qs[r][c]     = v.x * TANH_SCALE;
    qs[r][c + 1] = v.y * TANH_SCALE;
    if (tid < 128) wls[tid] = -2.0f * wv[tid];
  }
  const int VL = vlen[b];
  float Wsum = 0.0f;
  for (int h = 0; h < NH; ++h) Wsum += wv[h];  // uniform -> scalar loads

  float s[16];
#pragma unroll
  for (int t = 0; t < 16; ++t) {
    const int key0 = t * 64;
    __syncthreads();  // protect previous tile's reads
    {
      const int kr = tid >> 3;            // 0..63
      const int kc = (tid & 7) * 16;      // 0..112
      const float* src = &kp[(b * NLK + key0 + kr) * NH + kc];
      const float4 v0 = *(const float4*)&src[0];
      const float4 v1 = *(const float4*)&src[4];
      const float4 v2 = *(const float4*)&src[8];
      const float4 v3 = *(const float4*)&src[12];
      float* dst = &ks[kr][kc];
      dst[0]  = v0.x * TANH_SCALE; dst[1]  = v0.y * TANH_SCALE;
      dst[2]  = v0.z * TANH_SCALE; dst[3]  = v0.w * TANH_SCALE;
      dst[4]  = v1.x * TANH_SCALE; dst[5]  = v1.y * TANH_SCALE;
      dst[6]  = v1.z * TANH_SCALE; dst[7]  = v1.w * TANH_SCALE;
      dst[8]  = v2.x * TANH_SCALE; dst[9]  = v2.y * TANH_SCALE;
      dst[10] = v2.z * TANH_SCALE; dst[11] = v2.w * TANH_SCALE;
      dst[12] = v3.x * TANH_SCALE; dst[13] = v3.y * TANH_SCALE;
      dst[14] = v3.z * TANH_SCALE; dst[15] = v3.w * TANH_SCALE;
    }
    __syncthreads();

    float R = 0.0f;
#pragma unroll 4
    for (int h = 0; h < NH; ++h) {
      const float x = qs[wq][h] + ks[lane][h];     // already scaled: 2x*log2e
      const float e = fast_exp2(x);                // e^(2x)
      const float r = fast_rcp(1.0f + e);          // 1/(1+e^(2x))
      R = fmaf(wls[h], r, R);                      // += (-2w)*r
    }
    s[t] = Wsum + R;                               // = sum w*tanh(q+k)
    if (key0 + lane >= VL) s[t] = NEGV;
  }

  // masked softmax across 1024 = 16 regs x 64 lanes (wave-level)
  float m = s[0];
#pragma unroll
  for (int t = 1; t < 16; ++t) m = fmaxf(m, s[t]);
#pragma unroll
  for (int off = 32; off > 0; off >>= 1) m = fmaxf(m, __shfl_xor(m, off));

  float p[16];
  float sum = 0.0f;
#pragma unroll
  for (int t = 0; t < 16; ++t) {
    p[t] = fast_exp2((s[t] - m) * LOG2E);
    sum += p[t];
  }
#pragma unroll
  for (int off = 32; off > 0; off >>= 1) sum += __shfl_xor(sum, off);
  const float inv = fast_rcp(sum);

  float* arow = &attn[(b * NLQ + q0 + wq) * NLK];
#pragma unroll
  for (int t = 0; t < 16; ++t) arow[t * 64 + lane] = p[t] * inv;
}

// ---------------------------------------------------------------------------
extern "C" void kernel_launch(void* const* d_in, const int* in_sizes, int n_in,
                              void* d_out, int out_size, void* d_ws, size_t ws_size,
                              hipStream_t stream) {
  const float* Q    = (const float*)d_in[0];
  const float* Kin  = (const float*)d_in[1];
  const float* V    = (const float*)d_in[2];
  const int*   vlen = (const int*)d_in[3];
  const float* Wq   = (const float*)d_in[4];
  const float* Wk   = (const float*)d_in[5];
  const float* wv   = (const float*)d_in[6];
  float* out = (float*)d_out;

  float* qp   = (float*)d_ws;                       // 2048*128
  float* kp   = qp + NBATCH * NLQ * NH;             // 8192*128
  float* attn = kp + NBATCH * NLK * NH;             // 8*256*1024

  hipLaunchKernelGGL(proj_kernel, dim3(160, 2), dim3(256), 0, stream,
                     Q, Kin, Wq, Wk, qp, kp);
  hipLaunchKernelGGL(scores_softmax_kernel, dim3(NLQ / 8, NBATCH), dim3(512), 0, stream,
                     qp, kp, wv, vlen, attn);
  hipLaunchKernelGGL(pv_kernel, dim3(NLQ / 64, NDV / 64, NBATCH), dim3(256), 0, stream,
                     attn, V, out);
}